// Round 15
// baseline (12179.589 us; speedup 1.0000x reference)
//
#include <hip/hip_runtime.h>

// RNN-VAE on MI355X. R15 = R14 structure with the two measured bleeders fixed:
// (1) amdgpu_num_vgpr(256) on the step kernels so the U pins actually
//     materialize (R14: VGPR=128 -> 48-frag upin remat = 384 KB/step L2
//     re-stream). Pin U kt2-6 (160 regs); kt7 inline (hoisted).
// (2) z_x stored bf16 (32 KB/step/CU, half traffic) and double-buffer
//     PREFETCHED one step ahead (z is h-independent) so ingest hides under
//     the 64-MFMA step compute.
// Fallback (small ws): R8 verbatim (tagged MALL exchange, proven 4.96ms).

typedef __bf16 bf16x8 __attribute__((ext_vector_type(8)));
typedef float f32x4 __attribute__((ext_vector_type(4)));
typedef unsigned int uint4v __attribute__((ext_vector_type(4)));
typedef unsigned long long ull;
typedef unsigned short ushort;

#define DI __device__ __forceinline__

DI ushort f2bf(float f) {                    // fp32 -> bf16 RNE
  unsigned int u = __float_as_uint(f);
  u += 0x7fffu + ((u >> 16) & 1u);
  return (ushort)(u >> 16);
}
DI float sigf(float v) { return 1.0f / (1.0f + __expf(-v)); }

union FragU { bf16x8 v; ushort us[8]; };
union H8 { bf16x8 v; ull u[2]; uint4v q; };

DI f32x4 mfma16(bf16x8 a, bf16x8 b, f32x4 c) {
  // D[row=(lane>>4)*4+q][col=lane&15]; A[row=lane&15][k=(lane>>4)*8+j]
  return __builtin_amdgcn_mfma_f32_16x16x32_bf16(a, b, c, 0, 0, 0);
}
DI ull ald(const ull* p) {
  return __hip_atomic_load(p, __ATOMIC_RELAXED, __HIP_MEMORY_SCOPE_AGENT);
}

// ---- weight fragment packing ----
__global__ void pack_frags(const float* __restrict__ src,
                           ushort* __restrict__ dst, int K, int N) {
  int KT = K >> 5, NT = N >> 4;
  int total = KT * NT * 64;
  for (int idx = blockIdx.x * blockDim.x + threadIdx.x; idx < total;
       idx += gridDim.x * blockDim.x) {
    int lane = idx & 63;
    int fi = idx >> 6;
    int nt = fi % NT;
    int kt = fi / NT;
    int r0 = kt * 32 + (lane >> 4) * 8;
    int col = nt * 16 + (lane & 15);
    unsigned int w[4];
#pragma unroll
    for (int p = 0; p < 4; ++p) {
      unsigned int lo = f2bf(src[(size_t)(r0 + 2 * p) * N + col]);
      unsigned int hi = f2bf(src[(size_t)(r0 + 2 * p + 1) * N + col]);
      w[p] = lo | (hi << 16);
    }
    *(uint4v*)(dst + (size_t)idx * 8) = (uint4v){w[0], w[1], w[2], w[3]};
  }
}

// ---- per-(b,t) nonzero mask ----
__global__ void mask_flags(const float* __restrict__ x,
                           unsigned int* __restrict__ fmask) {
  const int t = blockIdx.x;
  const int b = threadIdx.x;
  const float* p = x + ((size_t)b * 1024 + t) * 128;
  bool nz = false;
#pragma unroll 8
  for (int k = 0; k < 32; ++k) {
    float4 v = *(const float4*)(p + k * 4);
    nz = nz || v.x != 0.f || v.y != 0.f || v.z != 0.f || v.w != 0.f;
  }
  unsigned long long bal = __ballot((int)nz);
  if ((threadIdx.x & 15) == 0)
    fmask[(size_t)(b >> 4) * 1024 + t] =
        (unsigned int)((bal >> (threadIdx.x & 48)) & 0xFFFFull);
}

// ======================= FAST PATH kernels ================================

// bias -> enc lat-frag buffer (fp32 frag layout)
__global__ void bias_frag(const float* __restrict__ bias,
                          float* __restrict__ latE) {
  for (int idx = threadIdx.x; idx < 64 * 64; idx += blockDim.x) {
    int nt = idx >> 6, lane = idx & 63;
    float v = bias[nt * 16 + (lane & 15)];
    f32x4 o = {v, v, v, v};
    *(f32x4*)(latE + (size_t)idx * 4) = o;
  }
}

// dec lat-frags: latD[g][nt][lane][q] = b_dec + h_fin[g] @ W_dec[64:]
__global__ void lat_dec(const ushort* __restrict__ hfin,
                        const ushort* __restrict__ WdLf,
                        const float* __restrict__ bdec,
                        float* __restrict__ latD) {
  const int g = blockIdx.x;
  const int tid = threadIdx.x;
  const int wv = tid >> 6, lane = tid & 63, l15 = lane & 15;
  const bf16x8* WLl = (const bf16x8*)WdLf + lane;
  bf16x8 ha[8];
#pragma unroll
  for (int kt = 0; kt < 8; ++kt)
    ha[kt] = *(const bf16x8*)&hfin[((size_t)g * 8 + kt) * 512 + lane * 8];
#pragma unroll
  for (int j = 0; j < 16; ++j) {
    int nt = wv * 16 + j;
    float bd = bdec[nt * 16 + l15];
    f32x4 acc = {bd, bd, bd, bd};
#pragma unroll
    for (int kt = 0; kt < 8; ++kt)
      acc = mfma16(ha[kt], WLl[(kt * 64 + nt) * 64], acc);
    *(f32x4*)(latD + ((size_t)g * 64 + nt) * 256 + lane * 4) = acc;
  }
}

// xW chunk GEMM -> bf16 packed z: zbuf[(trel*16+g)*16384 + nt*256 + lane*4]
template <int NKT>
__global__ void xw_gemm(const float* __restrict__ x,
                        const ushort* __restrict__ Bf,
                        const float* __restrict__ latf, int latGstride,
                        ushort* __restrict__ zbuf, int t0) {
  const int tg = blockIdx.x;
  const int trel = tg >> 4, g = tg & 15;
  const int t = t0 + trel;
  const int tid = threadIdx.x;
  const int wv = tid >> 6, lane = tid & 63;
  const int l15 = lane & 15, lkg = lane >> 4;

  const float* xp = x + ((size_t)(g * 16 + l15) * 1024 + t) * 128 + lkg * 8;
  FragU xf[NKT];
#pragma unroll
  for (int kt = 0; kt < NKT; ++kt) {
    float4 a = *(const float4*)(xp + kt * 32);
    float4 b = *(const float4*)(xp + kt * 32 + 4);
    xf[kt].us[0] = f2bf(a.x); xf[kt].us[1] = f2bf(a.y);
    xf[kt].us[2] = f2bf(a.z); xf[kt].us[3] = f2bf(a.w);
    xf[kt].us[4] = f2bf(b.x); xf[kt].us[5] = f2bf(b.y);
    xf[kt].us[6] = f2bf(b.z); xf[kt].us[7] = f2bf(b.w);
  }
  const bf16x8* Bl = (const bf16x8*)Bf + lane;
  const float* latg = latf + (size_t)g * latGstride;
  ushort* outb = zbuf + (size_t)(trel * 16 + g) * 16384;
#pragma unroll
  for (int j = 0; j < 16; ++j) {
    int nt = wv * 16 + j;
    f32x4 acc = *(const f32x4*)(latg + (size_t)nt * 256 + lane * 4);
#pragma unroll
    for (int kt = 0; kt < NKT; ++kt)
      acc = mfma16(xf[kt].v, Bl[(kt * 64 + nt) * 64], acc);
    uint2 z;
    z.x = (unsigned int)f2bf(acc[0]) | ((unsigned int)f2bf(acc[1]) << 16);
    z.y = (unsigned int)f2bf(acc[2]) | ((unsigned int)f2bf(acc[3]) << 16);
    *(uint2*)(outb + (size_t)nt * 256 + lane * 4) = z;
  }
}

// out chunk GEMM: out[b][t][:] = hchunk[b][t] @ W_out + b_out
__global__ void out_gemm(const ushort* __restrict__ hchunk,
                         const ushort* __restrict__ Wof,
                         const float* __restrict__ bout,
                         float* __restrict__ out, int t0) {
  const int g = blockIdx.x & 15;
  const int tq = blockIdx.x >> 4;
  const int tid = threadIdx.x;
  const int wv = tid >> 6, lane = tid & 63;
  const int l15 = lane & 15, lkg = lane >> 4;
  const int tc = tq * 4 + wv;
  const int t = t0 + tc;

  const ushort* hb = hchunk + (size_t)(tc * 16 + g) * 4096;
  bf16x8 ha[8];
#pragma unroll
  for (int kt = 0; kt < 8; ++kt)
    ha[kt] = *(const bf16x8*)&hb[kt * 512 + lane * 8];
  const bf16x8* Wl = (const bf16x8*)Wof + lane;
#pragma unroll
  for (int nt = 0; nt < 4; ++nt) {
    float bo = bout[nt * 16 + l15];
    f32x4 acc = {bo, bo, bo, bo};
#pragma unroll
    for (int kt = 0; kt < 8; ++kt)
      acc = mfma16(ha[kt], Wl[(kt * 4 + nt) * 64], acc);
#pragma unroll
    for (int q = 0; q < 4; ++q)
      out[((size_t)(g * 16 + lkg * 4 + q) * 1024 + t) * 64 + nt * 16 + l15] =
          acc[q];
  }
}

// ---- recurrence chunk kernels: 16 WGs, 512 thr, forced 256-VGPR budget ----
// Wave w owns h-col blocks cb in {2w, 2w+1}; pass P handles cb=2w+P.
// U: kt0,1 LDS; kt2-6 reg-pinned (160 VGPR); kt7 inline (hoisted).
// z: bf16 frags, double-buffered, prefetched one step ahead.

#define ZPREF(ZN, TN) do {                                                  \
    int tn_ = (TN); if (tn_ >= TC) tn_ = TC - 1;                            \
    const ushort* zp_ = zbuf + (size_t)(tn_ * 16 + g) * 16384 + lane * 4;   \
    _Pragma("unroll")                                                       \
    for (int P = 0; P < 2; ++P) {                                           \
      const int cb_ = 2 * w + P;                                            \
      _Pragma("unroll")                                                     \
      for (int j = 0; j < 4; ++j)                                           \
        (ZN)[P][j] = *(const uint2*)(zp_ + (size_t)(j * 16 + cb_) * 256);   \
    } } while (0)

#define PASS_ACC(ZC, P)                                                     \
    f32x4 acc[4];                                                           \
    _Pragma("unroll")                                                       \
    for (int j = 0; j < 4; ++j) {                                           \
      uint2 zz = (ZC)[P][j];                                                \
      acc[j] = (f32x4){__uint_as_float(zz.x << 16),                         \
                       __uint_as_float(zz.x & 0xFFFF0000u),                 \
                       __uint_as_float(zz.y << 16),                         \
                       __uint_as_float(zz.y & 0xFFFF0000u)};                \
    }                                                                       \
    _Pragma("unroll")                                                       \
    for (int kt = 0; kt < 2; ++kt) {                                        \
      bf16x8 h_ = *(const bf16x8*)&hstage[kt][lane][0];                     \
      _Pragma("unroll")                                                     \
      for (int j = 0; j < 4; ++j) {                                         \
        bf16x8 u_ =                                                         \
            *(const bf16x8*)&ulds[((kt * 64 + j * 16 + cb) * 64 + lane) * 8]; \
        acc[j] = mfma16(h_, u_, acc[j]);                                    \
      }                                                                     \
    }                                                                       \
    _Pragma("unroll")                                                       \
    for (int kt = 2; kt < 7; ++kt) {                                        \
      bf16x8 h_ = *(const bf16x8*)&hstage[kt][lane][0];                     \
      _Pragma("unroll")                                                     \
      for (int j = 0; j < 4; ++j)                                           \
        acc[j] = mfma16(h_, upin[kt - 2][P][j], acc[j]);                    \
    }                                                                       \
    {                                                                       \
      bf16x8 h_ = *(const bf16x8*)&hstage[7][lane][0];                      \
      _Pragma("unroll")                                                     \
      for (int j = 0; j < 4; ++j)                                           \
        acc[j] = mfma16(h_, Ul[(7 * 64 + j * 16 + cb) * 64], acc[j]);       \
    }

__global__ __launch_bounds__(512)
__attribute__((amdgpu_num_vgpr(256)))
void enc_step(const ushort* __restrict__ zbuf, const ushort* __restrict__ Uef,
              const unsigned int* __restrict__ fmask,
              float* __restrict__ cst, ushort* __restrict__ hst,
              ushort* __restrict__ hfin, int t0, int TC, int first, int last) {
  __shared__ __align__(16) ushort ulds[65536];        // U kt0,1: 128KB
  __shared__ __align__(16) ushort hstage[8][64][8];   // 8KB

  const int tid = threadIdx.x;
  const int w = tid >> 6, lane = tid & 63;
  const int l15 = lane & 15, lkg = lane >> 4;
  const int g = blockIdx.x;

#pragma unroll
  for (int k = 0; k < 16; ++k)
    ((uint4v*)ulds)[tid + k * 512] = ((const uint4v*)Uef)[tid + k * 512];

  const bf16x8* Ul = (const bf16x8*)Uef + lane;
  bf16x8 upin[5][2][4];                      // U kt2..6
#pragma unroll
  for (int k2 = 0; k2 < 5; ++k2)
#pragma unroll
    for (int P = 0; P < 2; ++P)
#pragma unroll
      for (int j = 0; j < 4; ++j)
        upin[k2][P][j] = Ul[((k2 + 2) * 64 + j * 16 + 2 * w + P) * 64];

  float c8[8];
  ushort hreg[8];
  if (first) {
#pragma unroll
    for (int i = 0; i < 8; ++i) { c8[i] = 0.f; hreg[i] = 0; }
    ((uint4v*)hstage)[tid] = (uint4v){0u, 0u, 0u, 0u};
  } else {
#pragma unroll
    for (int i = 0; i < 8; ++i) c8[i] = cst[((size_t)g * 512 + tid) * 8 + i];
    ((uint4v*)hstage)[tid] = ((const uint4v*)hst)[g * 512 + tid];
  }
  __syncthreads();
  if (!first) {
#pragma unroll
    for (int P = 0; P < 2; ++P)
#pragma unroll
      for (int q = 0; q < 4; ++q)
        hreg[P * 4 + q] =
            hstage[w][P * 32 + (l15 >> 3) * 16 + lkg * 4 + q][l15 & 7];
  }

  const unsigned int* flagp = fmask + (size_t)g * 1024 + t0;
  uint2 zA[2][4], zB[2][4];
  ZPREF(zA, 0);

#define ENC_BODY(ZC, ZN, TCI) do {                                          \
    ZPREF(ZN, (TCI) + 1);                                                   \
    const unsigned int flag = flagp[TCI];                                   \
    if (flag != 0u) {                                                       \
      ushort hv[8];                                                         \
      _Pragma("unroll")                                                     \
      for (int P = 0; P < 2; ++P) {                                         \
        const int cb = 2 * w + P;                                           \
        PASS_ACC(ZC, P)                                                     \
        _Pragma("unroll")                                                   \
        for (int q = 0; q < 4; ++q) {                                       \
          float iv = sigf(acc[0][q]);                                       \
          float fv = sigf(acc[1][q]);                                       \
          float gv = fmaxf(acc[2][q], 0.f);                                 \
          float ov = sigf(acc[3][q]);                                       \
          float cn = fv * c8[P * 4 + q] + iv * gv;                          \
          float hn = ov * fmaxf(cn, 0.f);                                   \
          bool m = (flag >> (lkg * 4 + q)) & 1u;                            \
          c8[P * 4 + q] = m ? cn : c8[P * 4 + q];                           \
          ushort hh = m ? f2bf(hn) : hreg[P * 4 + q];                       \
          hreg[P * 4 + q] = hh;                                             \
          hv[P * 4 + q] = hh;                                               \
        }                                                                   \
      }                                                                     \
      __syncthreads();                                                      \
      _Pragma("unroll")                                                     \
      for (int P = 0; P < 2; ++P)                                           \
        _Pragma("unroll")                                                   \
        for (int q = 0; q < 4; ++q)                                         \
          hstage[w][P * 32 + (l15 >> 3) * 16 + lkg * 4 + q][l15 & 7] =      \
              hv[P * 4 + q];                                                \
      __syncthreads();                                                      \
    } } while (0)

  for (int tc2 = 0; tc2 < TC; tc2 += 2) {
    ENC_BODY(zA, zB, tc2);
    ENC_BODY(zB, zA, tc2 + 1);
  }
#undef ENC_BODY

#pragma unroll
  for (int i = 0; i < 8; ++i) cst[((size_t)g * 512 + tid) * 8 + i] = c8[i];
  ((uint4v*)hst)[g * 512 + tid] = ((const uint4v*)hstage)[tid];
  if (last) ((uint4v*)hfin)[g * 512 + tid] = ((const uint4v*)hstage)[tid];
}

__global__ __launch_bounds__(512)
__attribute__((amdgpu_num_vgpr(256)))
void dec_step(const ushort* __restrict__ zbuf, const ushort* __restrict__ Udf,
              float* __restrict__ cst, ushort* __restrict__ hst,
              ushort* __restrict__ hchunk, int TC, int first) {
  __shared__ __align__(16) ushort ulds[65536];
  __shared__ __align__(16) ushort hstage[8][64][8];

  const int tid = threadIdx.x;
  const int w = tid >> 6, lane = tid & 63;
  const int l15 = lane & 15, lkg = lane >> 4;
  const int g = blockIdx.x;

#pragma unroll
  for (int k = 0; k < 16; ++k)
    ((uint4v*)ulds)[tid + k * 512] = ((const uint4v*)Udf)[tid + k * 512];

  const bf16x8* Ul = (const bf16x8*)Udf + lane;
  bf16x8 upin[5][2][4];                      // U kt2..6
#pragma unroll
  for (int k2 = 0; k2 < 5; ++k2)
#pragma unroll
    for (int P = 0; P < 2; ++P)
#pragma unroll
      for (int j = 0; j < 4; ++j)
        upin[k2][P][j] = Ul[((k2 + 2) * 64 + j * 16 + 2 * w + P) * 64];

  float c8[8];
  if (first) {
#pragma unroll
    for (int i = 0; i < 8; ++i) c8[i] = 0.f;
    ((uint4v*)hstage)[tid] = (uint4v){0u, 0u, 0u, 0u};
  } else {
#pragma unroll
    for (int i = 0; i < 8; ++i) c8[i] = cst[((size_t)g * 512 + tid) * 8 + i];
    ((uint4v*)hstage)[tid] = ((const uint4v*)hst)[g * 512 + tid];
  }
  __syncthreads();

  uint2 zA[2][4], zB[2][4];
  ZPREF(zA, 0);

#define DEC_BODY(ZC, ZN, TCI) do {                                          \
    ZPREF(ZN, (TCI) + 1);                                                   \
    ushort hv[8];                                                           \
    _Pragma("unroll")                                                       \
    for (int P = 0; P < 2; ++P) {                                           \
      const int cb = 2 * w + P;                                             \
      PASS_ACC(ZC, P)                                                       \
      _Pragma("unroll")                                                     \
      for (int q = 0; q < 4; ++q) {                                         \
        float iv = sigf(acc[0][q]);                                         \
        float fv = sigf(acc[1][q]);                                         \
        float gv = fmaxf(acc[2][q], 0.f);                                   \
        float ov = sigf(acc[3][q]);                                         \
        float cn = fv * c8[P * 4 + q] + iv * gv;                            \
        c8[P * 4 + q] = cn;                                                 \
        hv[P * 4 + q] = f2bf(ov * fmaxf(cn, 0.f));                          \
      }                                                                     \
    }                                                                       \
    __syncthreads();                                                        \
    _Pragma("unroll")                                                       \
    for (int P = 0; P < 2; ++P)                                             \
      _Pragma("unroll")                                                     \
      for (int q = 0; q < 4; ++q)                                           \
        hstage[w][P * 32 + (l15 >> 3) * 16 + lkg * 4 + q][l15 & 7] =        \
            hv[P * 4 + q];                                                  \
    __syncthreads();                                                        \
    ((uint4v*)hchunk)[(size_t)((TCI) * 16 + g) * 512 + tid] =               \
        ((const uint4v*)hstage)[tid];                                       \
  } while (0)

  for (int tc2 = 0; tc2 < TC; tc2 += 2) {
    DEC_BODY(zA, zB, tc2);
    DEC_BODY(zB, zA, tc2 + 1);
  }
#undef DEC_BODY

#pragma unroll
  for (int i = 0; i < 8; ++i) cst[((size_t)g * 512 + tid) * 8 + i] = c8[i];
  ((uint4v*)hst)[g * 512 + tid] = ((const uint4v*)hstage)[tid];
}

// ======================= R8 FALLBACK kernels ==============================

#define STORE_OWN(HX, PAR, TAG) do {                                        \
    if (tid < 128) {                                                        \
      const int kth = tid >> 6, word = tid & 63;                            \
      H8 hh; hh.q = *(const uint4v*)&hstage[2 * s + kth][word][0];          \
      const ull tg = (ull)(TAG);                                            \
      ull Aw = (hh.u[0] & 0xFFFFFFFFFFFFULL) | (tg << 48);                  \
      ull Bw = ((hh.u[0] >> 48) | ((hh.u[1] & 0xFFFFFFFFULL) << 16)) |      \
               (tg << 48);                                                  \
      ull Cw = (hh.u[1] >> 32) | (tg << 48);                                \
      ull* p_ = (HX) + (size_t)(g * 2 + (PAR)) * 1536 +                     \
                ((2 * s + kth) * 64 + word) * 3;                            \
      __hip_atomic_store(p_ + 0, Aw, __ATOMIC_RELAXED, __HIP_MEMORY_SCOPE_AGENT); \
      __hip_atomic_store(p_ + 1, Bw, __ATOMIC_RELAXED, __HIP_MEMORY_SCOPE_AGENT); \
      __hip_atomic_store(p_ + 2, Cw, __ATOMIC_RELAXED, __HIP_MEMORY_SCOPE_AGENT); \
    } } while (0)

#define POLL_REMOTE(HX, PAR, TAG) do {                                      \
    if (w >= 1) {                                                           \
      const int s2_ = (w - 1) + ((w - 1) >= s ? 1 : 0);                     \
      const int rk0 = 2 * s2_, rk1 = rk0 + 1;                               \
      const ull* hb_ = (HX) + (size_t)(g * 2 + (PAR)) * 1536;               \
      const ull* q0 = hb_ + (rk0 * 64 + lane) * 3;                          \
      const ull* q1 = hb_ + (rk1 * 64 + lane) * 3;                          \
      const ull tg = (ull)(TAG);                                            \
      ull A0, A1, A2, B0, B1, B2;                                           \
      unsigned it_ = 0;                                                     \
      for (;;) {                                                            \
        A0 = ald(q0); A1 = ald(q0 + 1); A2 = ald(q0 + 2);                   \
        B0 = ald(q1); B1 = ald(q1 + 1); B2 = ald(q1 + 2);                   \
        bool ok_ = ((A0 >> 48) == tg) && ((A1 >> 48) == tg) &&              \
                   ((A2 >> 48) == tg) && ((B0 >> 48) == tg) &&              \
                   ((B1 >> 48) == tg) && ((B2 >> 48) == tg);                \
        if (ok_ || ++it_ > (1u << 14)) break;                               \
      }                                                                     \
      H8 h0_, h1_;                                                          \
      h0_.u[0] = (A0 & 0xFFFFFFFFFFFFULL) | (A1 << 48);                     \
      h0_.u[1] = ((A1 >> 16) & 0xFFFFFFFFULL) | ((A2 & 0xFFFFFFFFULL) << 32); \
      h1_.u[0] = (B0 & 0xFFFFFFFFFFFFULL) | (B1 << 48);                     \
      h1_.u[1] = ((B1 >> 16) & 0xFFFFFFFFULL) | ((B2 & 0xFFFFFFFFULL) << 32); \
      *(uint4v*)&hstage[rk0][lane][0] = h0_.q;                              \
      *(uint4v*)&hstage[rk1][lane][0] = h1_.q;                              \
    } } while (0)

__global__ __launch_bounds__(256) __attribute__((amdgpu_waves_per_eu(1, 1)))
void enc_rnn(const float* __restrict__ x,
             const ushort* __restrict__ Wef, const ushort* __restrict__ Uef,
             const float* __restrict__ benc,
             const unsigned int* __restrict__ fmask,
             ull* __restrict__ hxE, ushort* __restrict__ hfin) {
  __shared__ __align__(16) ushort hstage[8][64][8];

  const int tid = threadIdx.x;
  const int w = tid >> 6, lane = tid & 63;
  const int l15 = lane & 15, lkg = lane >> 4;
  const int bid = blockIdx.x;
  const int s = bid >> 4, g = bid & 15;
  const int b0 = g * 16;
  int ntf[4];
#pragma unroll
  for (int G = 0; G < 4; ++G) ntf[G] = G * 16 + s * 4 + w;

  const bf16x8* Wl = (const bf16x8*)Wef + lane;
  const bf16x8* Ul = (const bf16x8*)Uef + lane;
  const unsigned int* flagp = fmask + (size_t)g * 1024;

  bf16x8 upin[8][4];
#pragma unroll
  for (int kt = 0; kt < 8; ++kt)
#pragma unroll
    for (int G = 0; G < 4; ++G) upin[kt][G] = Ul[(kt * 64 + ntf[G]) * 64];

  bf16x8 wpin[4][4];
#pragma unroll
  for (int G = 0; G < 4; ++G)
#pragma unroll
    for (int kt = 0; kt < 4; ++kt) wpin[G][kt] = Wl[(kt * 64 + ntf[G]) * 64];

  float bfr[4];
#pragma unroll
  for (int G = 0; G < 4; ++G) bfr[G] = benc[ntf[G] * 16 + l15];

  float c4[4];
  ushort hreg[4];
  bf16x8 hfr[8];
#pragma unroll
  for (int q = 0; q < 4; ++q) { c4[q] = 0.f; hreg[q] = 0; }
  H8 z_; z_.u[0] = 0; z_.u[1] = 0;
#pragma unroll
  for (int kt = 0; kt < 8; ++kt) hfr[kt] = z_.v;

  const float* xbase = x + (size_t)(b0 + l15) * 1024 * 128 + lkg * 8;
  const int kt_own = 2 * s + (w >> 1);
  const int lbase = (w & 1) * 32 + (l15 >> 3) * 16 + lkg * 4;
  const int jst = l15 & 7;
  int a = 0;
  bool xvalid = false;
  float4 xa[4][2];

  __syncthreads();

  for (int t = 0; t < 1024; ++t) {
    const unsigned int flag_t = flagp[t];
    if (flag_t == 0u) { xvalid = false; continue; }

    if (!xvalid) {
      const float* xp = xbase + (size_t)t * 128;
#pragma unroll
      for (int kt = 0; kt < 4; ++kt) {
        xa[kt][0] = *(const float4*)(xp + kt * 32);
        xa[kt][1] = *(const float4*)(xp + kt * 32 + 4);
      }
    }

    f32x4 acc[4];
#pragma unroll
    for (int G = 0; G < 4; ++G) acc[G] = (f32x4){bfr[G], bfr[G], bfr[G], bfr[G]};

    FragU xf[4];
#pragma unroll
    for (int kt = 0; kt < 4; ++kt) {
      xf[kt].us[0] = f2bf(xa[kt][0].x); xf[kt].us[1] = f2bf(xa[kt][0].y);
      xf[kt].us[2] = f2bf(xa[kt][0].z); xf[kt].us[3] = f2bf(xa[kt][0].w);
      xf[kt].us[4] = f2bf(xa[kt][1].x); xf[kt].us[5] = f2bf(xa[kt][1].y);
      xf[kt].us[6] = f2bf(xa[kt][1].z); xf[kt].us[7] = f2bf(xa[kt][1].w);
    }
#pragma unroll
    for (int kt = 0; kt < 4; ++kt)
#pragma unroll
      for (int G = 0; G < 4; ++G) acc[G] = mfma16(xf[kt].v, wpin[G][kt], acc[G]);

#pragma unroll
    for (int kt = 0; kt < 8; ++kt)
#pragma unroll
      for (int G = 0; G < 4; ++G) acc[G] = mfma16(hfr[kt], upin[kt][G], acc[G]);

    ushort hv[4];
#pragma unroll
    for (int q = 0; q < 4; ++q) {
      float iv = sigf(acc[0][q]);
      float fv = sigf(acc[1][q]);
      float gv = fmaxf(acc[2][q], 0.f);
      float ov = sigf(acc[3][q]);
      float cn = fv * c4[q] + iv * gv;
      float hn = ov * fmaxf(cn, 0.f);
      bool m = (flag_t >> (lkg * 4 + q)) & 1u;
      c4[q] = m ? cn : c4[q];
      ushort hh = m ? f2bf(hn) : hreg[q];
      hreg[q] = hh;
      hv[q] = hh;
    }

    __syncthreads();
#pragma unroll
    for (int q = 0; q < 4; ++q) hstage[kt_own][lbase + q][jst] = hv[q];
    __syncthreads();

    STORE_OWN(hxE, (a & 1), a + 1);

    if (t < 1023) {
      const float* xq = xbase + (size_t)(t + 1) * 128;
#pragma unroll
      for (int kt = 0; kt < 4; ++kt) {
        xa[kt][0] = *(const float4*)(xq + kt * 32);
        xa[kt][1] = *(const float4*)(xq + kt * 32 + 4);
      }
      xvalid = true;
    } else xvalid = false;

    POLL_REMOTE(hxE, (a & 1), a + 1);
    __syncthreads();

#pragma unroll
    for (int kt = 0; kt < 8; ++kt)
      hfr[kt] = *(const bf16x8*)&hstage[kt][lane][0];
    ++a;
  }

  if (w < 2) {
    int kt = 2 * s + w;
    H8 hh_; hh_.v = hfr[kt];
    *(uint4v*)&hfin[((size_t)g * 8 + kt) * 512 + lane * 8] = hh_.q;
  }
}

__global__ __launch_bounds__(256) __attribute__((amdgpu_waves_per_eu(1, 1)))
void dec_rnn(const float* __restrict__ x,
             const ushort* __restrict__ Wd0f, const ushort* __restrict__ WdLf,
             const ushort* __restrict__ Udf,
             const float* __restrict__ bdec, const ushort* __restrict__ Wof,
             const float* __restrict__ bout, const ushort* __restrict__ hfin,
             ull* __restrict__ hxD, float* __restrict__ out) {
  __shared__ __align__(16) ushort hstage[8][64][8];

  const int tid = threadIdx.x;
  const int w = tid >> 6, lane = tid & 63;
  const int l15 = lane & 15, lkg = lane >> 4;
  const int bid = blockIdx.x;
  const int s = bid >> 4, g = bid & 15;
  const int b0 = g * 16;
  int ntf[4];
#pragma unroll
  for (int G = 0; G < 4; ++G) ntf[G] = G * 16 + s * 4 + w;

  const bf16x8* W0l = (const bf16x8*)Wd0f + lane;
  const bf16x8* WLl = (const bf16x8*)WdLf + lane;
  const bf16x8* Ul  = (const bf16x8*)Udf + lane;

  bf16x8 upin[8][4];
#pragma unroll
  for (int kt = 0; kt < 8; ++kt)
#pragma unroll
    for (int G = 0; G < 4; ++G) upin[kt][G] = Ul[(kt * 64 + ntf[G]) * 64];

  bf16x8 w0pin[4][2];
#pragma unroll
  for (int G = 0; G < 4; ++G)
#pragma unroll
    for (int kt = 0; kt < 2; ++kt) w0pin[G][kt] = W0l[(kt * 64 + ntf[G]) * 64];

  f32x4 lat[4];
  {
    bf16x8 ha[8];
#pragma unroll
    for (int kt = 0; kt < 8; ++kt)
      ha[kt] = *(const bf16x8*)&hfin[((size_t)g * 8 + kt) * 512 + lane * 8];
#pragma unroll
    for (int G = 0; G < 4; ++G) {
      float bd = bdec[ntf[G] * 16 + l15];
      lat[G] = (f32x4){bd, bd, bd, bd};
    }
#pragma unroll
    for (int kt = 0; kt < 8; ++kt)
#pragma unroll
      for (int G = 0; G < 4; ++G)
        lat[G] = mfma16(ha[kt], WLl[(kt * 64 + ntf[G]) * 64], lat[G]);
  }

  bf16x8 wofr[8];
  if (w == 0) {
#pragma unroll
    for (int kt = 0; kt < 8; ++kt)
      wofr[kt] = ((const bf16x8*)Wof)[(kt * 4 + s) * 64 + lane];
  }
  const float bo = bout[s * 16 + l15];

  float c4[4];
  bf16x8 hfr[8];
#pragma unroll
  for (int q = 0; q < 4; ++q) c4[q] = 0.f;
  H8 z_; z_.u[0] = 0; z_.u[1] = 0;
#pragma unroll
  for (int kt = 0; kt < 8; ++kt) hfr[kt] = z_.v;

  const float* xbase = x + (size_t)(b0 + l15) * 1024 * 128 + lkg * 8;
  const int kt_own = 2 * s + (w >> 1);
  const int lbase = (w & 1) * 32 + (l15 >> 3) * 16 + lkg * 4;
  const int jst = l15 & 7;

  float4 xa[2][2];
  xa[0][0] = *(const float4*)(xbase);      xa[0][1] = *(const float4*)(xbase + 4);
  xa[1][0] = *(const float4*)(xbase + 32); xa[1][1] = *(const float4*)(xbase + 36);

  __syncthreads();

  for (int t = 0; t < 1024; ++t) {
    f32x4 acc[4];
#pragma unroll
    for (int G = 0; G < 4; ++G) acc[G] = lat[G];

    FragU xf[2];
#pragma unroll
    for (int kt = 0; kt < 2; ++kt) {
      xf[kt].us[0] = f2bf(xa[kt][0].x); xf[kt].us[1] = f2bf(xa[kt][0].y);
      xf[kt].us[2] = f2bf(xa[kt][0].z); xf[kt].us[3] = f2bf(xa[kt][0].w);
      xf[kt].us[4] = f2bf(xa[kt][1].x); xf[kt].us[5] = f2bf(xa[kt][1].y);
      xf[kt].us[6] = f2bf(xa[kt][1].z); xf[kt].us[7] = f2bf(xa[kt][1].w);
    }
#pragma unroll
    for (int kt = 0; kt < 2; ++kt)
#pragma unroll
      for (int G = 0; G < 4; ++G) acc[G] = mfma16(xf[kt].v, w0pin[G][kt], acc[G]);

#pragma unroll
    for (int kt = 0; kt < 8; ++kt)
#pragma unroll
      for (int G = 0; G < 4; ++G) acc[G] = mfma16(hfr[kt], upin[kt][G], acc[G]);

    ushort hv[4];
#pragma unroll
    for (int q = 0; q < 4; ++q) {
      float iv = sigf(acc[0][q]);
      float fv = sigf(acc[1][q]);
      float gv = fmaxf(acc[2][q], 0.f);
      float ov = sigf(acc[3][q]);
      float cn = fv * c4[q] + iv * gv;
      float hn = ov * fmaxf(cn, 0.f);
      c4[q] = cn;
      hv[q] = f2bf(hn);
    }

    __syncthreads();
#pragma unroll
    for (int q = 0; q < 4; ++q) hstage[kt_own][lbase + q][jst] = hv[q];
    __syncthreads();

    STORE_OWN(hxD, (t & 1), t + 1);

    if (t > 0 && w == 0) {
      f32x4 oa = {bo, bo, bo, bo};
#pragma unroll
      for (int kt = 0; kt < 8; ++kt) oa = mfma16(hfr[kt], wofr[kt], oa);
#pragma unroll
      for (int q = 0; q < 4; ++q)
        out[((size_t)(b0 + lkg * 4 + q) * 1024 + (t - 1)) * 64 + s * 16 + l15] = oa[q];
    }
    if (t < 1023) {
      const float* xq = xbase + (size_t)(t + 1) * 128;
      xa[0][0] = *(const float4*)(xq);      xa[0][1] = *(const float4*)(xq + 4);
      xa[1][0] = *(const float4*)(xq + 32); xa[1][1] = *(const float4*)(xq + 36);
    }

    POLL_REMOTE(hxD, (t & 1), t + 1);
    __syncthreads();

#pragma unroll
    for (int kt = 0; kt < 8; ++kt)
      hfr[kt] = *(const bf16x8*)&hstage[kt][lane][0];
  }

  if (w == 0) {
    f32x4 oa = {bo, bo, bo, bo};
#pragma unroll
    for (int kt = 0; kt < 8; ++kt) oa = mfma16(hfr[kt], wofr[kt], oa);
#pragma unroll
    for (int q = 0; q < 4; ++q)
      out[((size_t)(b0 + lkg * 4 + q) * 1024 + 1023) * 64 + s * 16 + l15] = oa[q];
  }
}

// =========================================================================
extern "C" void kernel_launch(void* const* d_in, const int* in_sizes, int n_in,
                              void* d_out, int out_size, void* d_ws, size_t ws_size,
                              hipStream_t stream) {
  const float* inputs = (const float*)d_in[0];
  const float* W_enc  = (const float*)d_in[1];
  const float* U_enc  = (const float*)d_in[2];
  const float* b_enc  = (const float*)d_in[3];
  const float* W_dec  = (const float*)d_in[4];
  const float* U_dec  = (const float*)d_in[5];
  const float* b_dec  = (const float*)d_in[6];
  const float* W_out  = (const float*)d_in[7];
  const float* b_out  = (const float*)d_in[8];

  // ---- workspace map (R14-verified, non-overlapping) ----
  char* ws = (char*)d_ws;
  ushort* Uef   = (ushort*)(ws + 0);              // 524288
  ushort* Udf   = (ushort*)(ws + 524288);         // 524288
  ushort* Wef   = (ushort*)(ws + 1048576);        // 262144
  ushort* Wd0f  = (ushort*)(ws + 1310720);        // 131072
  ushort* WdLf  = (ushort*)(ws + 1441792);        // 524288
  ushort* Wof   = (ushort*)(ws + 1966080);        // 32768
  ushort* hfin  = (ushort*)(ws + 1998848);        // 131072
  unsigned int* fmask = (unsigned int*)(ws + 2129920);  // 65536
  ull*    hxE   = (ull*)(ws + 2195456);           // 393216
  ull*    hxD   = (ull*)(ws + 2588672);           // 393216
  float*  latE  = (float*)(ws + 2981888);         // 65536   -> 3047424
  float*  latD  = (float*)(ws + 3047424);         // 1048576 -> 4096000
  float*  cstE  = (float*)(ws + 4096000);         // 262144  -> 4358144
  ushort* hstE  = (ushort*)(ws + 4358144);        // 131072  -> 4489216
  float*  cstD  = (float*)(ws + 4489216);         // 262144  -> 4751360
  ushort* hstD  = (ushort*)(ws + 4751360);        // 131072  -> 4882432
  const size_t base = 4882432;

  // per-chunk: hchunk TC*131072 + zbuf(bf16) TC*524288
  int TC = 0;
  if (ws_size >= base + (size_t)128 * (131072 + 524288)) TC = 128;
  else if (ws_size >= base + (size_t)64 * (131072 + 524288)) TC = 64;
  else if (ws_size >= base + (size_t)32 * (131072 + 524288)) TC = 32;

  mask_flags<<<1024, 256, 0, stream>>>(inputs, fmask);
  pack_frags<<<128, 256, 0, stream>>>(U_enc, Uef, 256, 1024);
  pack_frags<<<128, 256, 0, stream>>>(U_dec, Udf, 256, 1024);
  pack_frags<<<128, 256, 0, stream>>>(W_enc, Wef, 128, 1024);
  pack_frags<<<128, 256, 0, stream>>>(W_dec, Wd0f, 64, 1024);
  pack_frags<<<128, 256, 0, stream>>>(W_dec + 64 * 1024, WdLf, 256, 1024);
  pack_frags<<<32, 256, 0, stream>>>(W_out, Wof, 256, 64);

  if (TC) {
    ushort* hchunk = (ushort*)(ws + base);
    ushort* zbuf   = (ushort*)(ws + base + (size_t)TC * 131072);
    const int NC = 1024 / TC;

    bias_frag<<<1, 256, 0, stream>>>(b_enc, latE);
    for (int c = 0; c < NC; ++c) {
      xw_gemm<4><<<TC * 16, 256, 0, stream>>>(inputs, Wef, latE, 0, zbuf,
                                              c * TC);
      enc_step<<<16, 512, 0, stream>>>(zbuf, Uef, fmask, cstE, hstE, hfin,
                                       c * TC, TC, c == 0, c == NC - 1);
    }
    lat_dec<<<16, 256, 0, stream>>>(hfin, WdLf, b_dec, latD);
    for (int c = 0; c < NC; ++c) {
      xw_gemm<2><<<TC * 16, 256, 0, stream>>>(inputs, Wd0f, latD, 64 * 256,
                                              zbuf, c * TC);
      dec_step<<<16, 512, 0, stream>>>(zbuf, Udf, cstD, hstD, hchunk, TC,
                                       c == 0);
      out_gemm<<<16 * (TC / 4), 256, 0, stream>>>(hchunk, Wof, b_out,
                                                  (float*)d_out, c * TC);
    }
  } else {
    enc_rnn<<<64, 256, 0, stream>>>(inputs, Wef, Uef, b_enc, fmask, hxE, hfin);
    dec_rnn<<<64, 256, 0, stream>>>(inputs, Wd0f, WdLf, Udf, b_dec, Wof, b_out,
                                    hfin, hxD, (float*)d_out);
  }
}

// Round 16
// 8245.193 us; speedup vs baseline: 1.4772x; 1.4772x over previous
//
#include <hip/hip_runtime.h>

// RNN-VAE on MI355X. R16 = R10 (paired groups, PASSING) with the poll chain
// MERGED: one store->visible->detect exchange chain per PAIR of group-steps
// instead of two serial ones (R10's measured defect). 32 WGs = 4 N-split x
// 8 pairs; 256 thr, waves_per_eu(1,1) (proven 244-VGPR budget); U fully
// reg-pinned, shared weight pins; tagged self-validating 8B words at agent
// scope; waves 1-3 poll BOTH groups' 2 kt-slices in one loop; wave 0 runs
// both dec out-projs(t-1) in the poll window. 3 barriers/combined-step.

typedef __bf16 bf16x8 __attribute__((ext_vector_type(8)));
typedef float f32x4 __attribute__((ext_vector_type(4)));
typedef unsigned int uint4v __attribute__((ext_vector_type(4)));
typedef unsigned long long ull;
typedef unsigned short ushort;

#define DI __device__ __forceinline__

DI ushort f2bf(float f) {                    // fp32 -> bf16 RNE
  unsigned int u = __float_as_uint(f);
  u += 0x7fffu + ((u >> 16) & 1u);
  return (ushort)(u >> 16);
}
DI float sigf(float v) { return 1.0f / (1.0f + __expf(-v)); }

union FragU { bf16x8 v; ushort us[8]; };
union H8 { bf16x8 v; ull u[2]; uint4v q; };

DI f32x4 mfma16(bf16x8 a, bf16x8 b, f32x4 c) {
  return __builtin_amdgcn_mfma_f32_16x16x32_bf16(a, b, c, 0, 0, 0);
}
DI ull ald(const ull* p) {
  return __hip_atomic_load(p, __ATOMIC_RELAXED, __HIP_MEMORY_SCOPE_AGENT);
}

// ---- weight fragment packing (unchanged) ----
__global__ void pack_frags(const float* __restrict__ src,
                           ushort* __restrict__ dst, int K, int N) {
  int KT = K >> 5, NT = N >> 4;
  int total = KT * NT * 64;
  for (int idx = blockIdx.x * blockDim.x + threadIdx.x; idx < total;
       idx += gridDim.x * blockDim.x) {
    int lane = idx & 63;
    int fi = idx >> 6;
    int nt = fi % NT;
    int kt = fi / NT;
    int r0 = kt * 32 + (lane >> 4) * 8;
    int col = nt * 16 + (lane & 15);
    unsigned int w[4];
#pragma unroll
    for (int p = 0; p < 4; ++p) {
      unsigned int lo = f2bf(src[(size_t)(r0 + 2 * p) * N + col]);
      unsigned int hi = f2bf(src[(size_t)(r0 + 2 * p + 1) * N + col]);
      w[p] = lo | (hi << 16);
    }
    *(uint4v*)(dst + (size_t)idx * 8) = (uint4v){w[0], w[1], w[2], w[3]};
  }
}

// ---- per-(b,t) nonzero mask (unchanged) ----
__global__ void mask_flags(const float* __restrict__ x,
                           unsigned int* __restrict__ fmask) {
  const int t = blockIdx.x;
  const int b = threadIdx.x;
  const float* p = x + ((size_t)b * 1024 + t) * 128;
  bool nz = false;
#pragma unroll 8
  for (int k = 0; k < 32; ++k) {
    float4 v = *(const float4*)(p + k * 4);
    nz = nz || v.x != 0.f || v.y != 0.f || v.z != 0.f || v.w != 0.f;
  }
  unsigned long long bal = __ballot((int)nz);
  if ((threadIdx.x & 15) == 0)
    fmask[(size_t)(b >> 4) * 1024 + t] =
        (unsigned int)((bal >> (threadIdx.x & 48)) & 0xFFFFull);
}

// store own 2 kt-slices of HSTG as tagged 3-ull words (tid<128)
#define STORE_OWN(HSTG, HX, G, PAR, TAG) do {                               \
    if (tid < 128) {                                                        \
      const int kth = tid >> 6, word = tid & 63;                            \
      H8 hh; hh.q = *(const uint4v*)&(HSTG)[2 * s + kth][word][0];          \
      const ull tg = (ull)(TAG);                                            \
      ull Aw = (hh.u[0] & 0xFFFFFFFFFFFFULL) | (tg << 48);                  \
      ull Bw = ((hh.u[0] >> 48) | ((hh.u[1] & 0xFFFFFFFFULL) << 16)) |      \
               (tg << 48);                                                  \
      ull Cw = (hh.u[1] >> 32) | (tg << 48);                                \
      ull* p_ = (HX) + (size_t)((G) * 2 + (PAR)) * 1536 +                   \
                ((2 * s + kth) * 64 + word) * 3;                            \
      __hip_atomic_store(p_ + 0, Aw, __ATOMIC_RELAXED, __HIP_MEMORY_SCOPE_AGENT); \
      __hip_atomic_store(p_ + 1, Bw, __ATOMIC_RELAXED, __HIP_MEMORY_SCOPE_AGENT); \
      __hip_atomic_store(p_ + 2, Cw, __ATOMIC_RELAXED, __HIP_MEMORY_SCOPE_AGENT); \
    } } while (0)

// waves 1..3: merged poll of BOTH groups' partner slices (one chain)
#define POLL2(HX, DOA, DOB, PARA, PARB, TAGA, TAGB) do {                    \
    if (w >= 1) {                                                           \
      const int s2_ = (w - 1) + ((w - 1) >= s ? 1 : 0);                     \
      const int rk0 = 2 * s2_, rk1 = rk0 + 1;                               \
      const ull* hbA_ = (HX) + (size_t)(gA * 2 + (PARA)) * 1536;            \
      const ull* hbB_ = (HX) + (size_t)(gB * 2 + (PARB)) * 1536;            \
      const ull* qA0 = hbA_ + (rk0 * 64 + lane) * 3;                        \
      const ull* qA1 = hbA_ + (rk1 * 64 + lane) * 3;                        \
      const ull* qB0 = hbB_ + (rk0 * 64 + lane) * 3;                        \
      const ull* qB1 = hbB_ + (rk1 * 64 + lane) * 3;                        \
      const ull tgA = (ull)(TAGA), tgB = (ull)(TAGB);                       \
      ull A0=0,A1=0,A2=0,A3=0,A4=0,A5=0;                                    \
      ull B0=0,B1=0,B2=0,B3=0,B4=0,B5=0;                                    \
      unsigned it_ = 0;                                                     \
      for (;;) {                                                            \
        if (DOA) { A0=ald(qA0); A1=ald(qA0+1); A2=ald(qA0+2);               \
                   A3=ald(qA1); A4=ald(qA1+1); A5=ald(qA1+2); }             \
        if (DOB) { B0=ald(qB0); B1=ald(qB0+1); B2=ald(qB0+2);               \
                   B3=ald(qB1); B4=ald(qB1+1); B5=ald(qB1+2); }             \
        bool okA = !(DOA) || (((A0>>48)==tgA) && ((A1>>48)==tgA) &&         \
                   ((A2>>48)==tgA) && ((A3>>48)==tgA) &&                    \
                   ((A4>>48)==tgA) && ((A5>>48)==tgA));                     \
        bool okB = !(DOB) || (((B0>>48)==tgB) && ((B1>>48)==tgB) &&         \
                   ((B2>>48)==tgB) && ((B3>>48)==tgB) &&                    \
                   ((B4>>48)==tgB) && ((B5>>48)==tgB));                     \
        if ((okA && okB) || ++it_ > (1u << 14)) break;                      \
      }                                                                     \
      if (DOA) {                                                            \
        H8 h0_, h1_;                                                        \
        h0_.u[0] = (A0 & 0xFFFFFFFFFFFFULL) | (A1 << 48);                   \
        h0_.u[1] = ((A1 >> 16) & 0xFFFFFFFFULL) | ((A2 & 0xFFFFFFFFULL) << 32); \
        h1_.u[0] = (A3 & 0xFFFFFFFFFFFFULL) | (A4 << 48);                   \
        h1_.u[1] = ((A4 >> 16) & 0xFFFFFFFFULL) | ((A5 & 0xFFFFFFFFULL) << 32); \
        *(uint4v*)&hstA[rk0][lane][0] = h0_.q;                              \
        *(uint4v*)&hstA[rk1][lane][0] = h1_.q;                              \
      }                                                                     \
      if (DOB) {                                                            \
        H8 h0_, h1_;                                                        \
        h0_.u[0] = (B0 & 0xFFFFFFFFFFFFULL) | (B1 << 48);                   \
        h0_.u[1] = ((B1 >> 16) & 0xFFFFFFFFULL) | ((B2 & 0xFFFFFFFFULL) << 32); \
        h1_.u[0] = (B3 & 0xFFFFFFFFFFFFULL) | (B4 << 48);                   \
        h1_.u[1] = ((B4 >> 16) & 0xFFFFFFFFULL) | ((B5 & 0xFFFFFFFFULL) << 32); \
        *(uint4v*)&hstB[rk0][lane][0] = h0_.q;                              \
        *(uint4v*)&hstB[rk1][lane][0] = h1_.q;                              \
      }                                                                     \
    } } while (0)

// =========================== encoder ======================================
__global__ __launch_bounds__(256) __attribute__((amdgpu_waves_per_eu(1, 1)))
void enc_rnn(const float* __restrict__ x,
             const ushort* __restrict__ Wef,
             const ushort* __restrict__ Uef,
             const float* __restrict__ benc,
             const unsigned int* __restrict__ fmask,
             ull* __restrict__ hxE,
             ushort* __restrict__ hfin) {
  __shared__ __align__(16) ushort hstA[8][64][8];   // 8KB
  __shared__ __align__(16) ushort hstB[8][64][8];   // 8KB

  const int tid = threadIdx.x;
  const int w = tid >> 6, lane = tid & 63;
  const int l15 = lane & 15, lkg = lane >> 4;
  const int bid = blockIdx.x;
  const int s = bid >> 3, p = bid & 7;
  const int gA = 2 * p, gB = 2 * p + 1;
  int ntf[4];
#pragma unroll
  for (int G = 0; G < 4; ++G) ntf[G] = G * 16 + s * 4 + w;

  const bf16x8* Wl = (const bf16x8*)Wef + lane;
  const bf16x8* Ul = (const bf16x8*)Uef + lane;

  bf16x8 upin[8][4];                         // U slice, shared by A and B
#pragma unroll
  for (int kt = 0; kt < 8; ++kt)
#pragma unroll
    for (int G = 0; G < 4; ++G) upin[kt][G] = Ul[(kt * 64 + ntf[G]) * 64];

  bf16x8 wpin[4][4];                         // W kt0..3, shared
#pragma unroll
  for (int G = 0; G < 4; ++G)
#pragma unroll
    for (int kt = 0; kt < 4; ++kt) wpin[G][kt] = Wl[(kt * 64 + ntf[G]) * 64];

  float bfr[4];
#pragma unroll
  for (int G = 0; G < 4; ++G) bfr[G] = benc[ntf[G] * 16 + l15];

  float cA[4], cB[4];
  ushort hgA[4], hgB[4];
  bf16x8 hfA[8], hfB[8];
#pragma unroll
  for (int q = 0; q < 4; ++q) { cA[q] = 0.f; cB[q] = 0.f; hgA[q] = 0; hgB[q] = 0; }
  H8 z_; z_.u[0] = 0; z_.u[1] = 0;
#pragma unroll
  for (int kt = 0; kt < 8; ++kt) { hfA[kt] = z_.v; hfB[kt] = z_.v; }

  const float* xbA = x + (size_t)(gA * 16 + l15) * 1024 * 128 + lkg * 8;
  const float* xbB = x + (size_t)(gB * 16 + l15) * 1024 * 128 + lkg * 8;
  const unsigned int* fpA = fmask + (size_t)gA * 1024;
  const unsigned int* fpB = fmask + (size_t)gB * 1024;
  const int kt_own = 2 * s + (w >> 1);
  const int lbase = (w & 1) * 32 + (l15 >> 3) * 16 + lkg * 4;
  const int jst = l15 & 7;
  int aA = 0, aB = 0;
  bool xvA = false, xvB = false;
  float4 xaA[4][2], xaB[4][2];

  __syncthreads();

  for (int t = 0; t < 1024; ++t) {
    const unsigned int flA = fpA[t], flB = fpB[t];
    if (flA == 0u && flB == 0u) { xvA = false; xvB = false; continue; }
    const bool doA = flA != 0u, doB = flB != 0u;

    ushort hvA[4], hvB[4];

    if (doA) {                               // ---- A compute ----
      if (!xvA) {
        const float* xp = xbA + (size_t)t * 128;
#pragma unroll
        for (int kt = 0; kt < 4; ++kt) {
          xaA[kt][0] = *(const float4*)(xp + kt * 32);
          xaA[kt][1] = *(const float4*)(xp + kt * 32 + 4);
        }
      }
      f32x4 acc[4];
#pragma unroll
      for (int G = 0; G < 4; ++G) acc[G] = (f32x4){bfr[G], bfr[G], bfr[G], bfr[G]};
      FragU xf[4];
#pragma unroll
      for (int kt = 0; kt < 4; ++kt) {
        xf[kt].us[0] = f2bf(xaA[kt][0].x); xf[kt].us[1] = f2bf(xaA[kt][0].y);
        xf[kt].us[2] = f2bf(xaA[kt][0].z); xf[kt].us[3] = f2bf(xaA[kt][0].w);
        xf[kt].us[4] = f2bf(xaA[kt][1].x); xf[kt].us[5] = f2bf(xaA[kt][1].y);
        xf[kt].us[6] = f2bf(xaA[kt][1].z); xf[kt].us[7] = f2bf(xaA[kt][1].w);
      }
#pragma unroll
      for (int kt = 0; kt < 4; ++kt)
#pragma unroll
        for (int G = 0; G < 4; ++G) acc[G] = mfma16(xf[kt].v, wpin[G][kt], acc[G]);
#pragma unroll
      for (int kt = 0; kt < 8; ++kt)
#pragma unroll
        for (int G = 0; G < 4; ++G) acc[G] = mfma16(hfA[kt], upin[kt][G], acc[G]);
#pragma unroll
      for (int q = 0; q < 4; ++q) {
        float iv = sigf(acc[0][q]);
        float fv = sigf(acc[1][q]);
        float gv = fmaxf(acc[2][q], 0.f);
        float ov = sigf(acc[3][q]);
        float cn = fv * cA[q] + iv * gv;
        float hn = ov * fmaxf(cn, 0.f);
        bool m = (flA >> (lkg * 4 + q)) & 1u;
        cA[q] = m ? cn : cA[q];
        ushort hh = m ? f2bf(hn) : hgA[q];
        hgA[q] = hh; hvA[q] = hh;
      }
    }

    if (doB) {                               // ---- B compute ----
      if (!xvB) {
        const float* xp = xbB + (size_t)t * 128;
#pragma unroll
        for (int kt = 0; kt < 4; ++kt) {
          xaB[kt][0] = *(const float4*)(xp + kt * 32);
          xaB[kt][1] = *(const float4*)(xp + kt * 32 + 4);
        }
      }
      f32x4 acc[4];
#pragma unroll
      for (int G = 0; G < 4; ++G) acc[G] = (f32x4){bfr[G], bfr[G], bfr[G], bfr[G]};
      FragU xf[4];
#pragma unroll
      for (int kt = 0; kt < 4; ++kt) {
        xf[kt].us[0] = f2bf(xaB[kt][0].x); xf[kt].us[1] = f2bf(xaB[kt][0].y);
        xf[kt].us[2] = f2bf(xaB[kt][0].z); xf[kt].us[3] = f2bf(xaB[kt][0].w);
        xf[kt].us[4] = f2bf(xaB[kt][1].x); xf[kt].us[5] = f2bf(xaB[kt][1].y);
        xf[kt].us[6] = f2bf(xaB[kt][1].z); xf[kt].us[7] = f2bf(xaB[kt][1].w);
      }
#pragma unroll
      for (int kt = 0; kt < 4; ++kt)
#pragma unroll
        for (int G = 0; G < 4; ++G) acc[G] = mfma16(xf[kt].v, wpin[G][kt], acc[G]);
#pragma unroll
      for (int kt = 0; kt < 8; ++kt)
#pragma unroll
        for (int G = 0; G < 4; ++G) acc[G] = mfma16(hfB[kt], upin[kt][G], acc[G]);
#pragma unroll
      for (int q = 0; q < 4; ++q) {
        float iv = sigf(acc[0][q]);
        float fv = sigf(acc[1][q]);
        float gv = fmaxf(acc[2][q], 0.f);
        float ov = sigf(acc[3][q]);
        float cn = fv * cB[q] + iv * gv;
        float hn = ov * fmaxf(cn, 0.f);
        bool m = (flB >> (lkg * 4 + q)) & 1u;
        cB[q] = m ? cn : cB[q];
        ushort hh = m ? f2bf(hn) : hgB[q];
        hgB[q] = hh; hvB[q] = hh;
      }
    }

    __syncthreads();                         // b1: prior hst reads done
    if (doA) {
#pragma unroll
      for (int q = 0; q < 4; ++q) hstA[kt_own][lbase + q][jst] = hvA[q];
    }
    if (doB) {
#pragma unroll
      for (int q = 0; q < 4; ++q) hstB[kt_own][lbase + q][jst] = hvB[q];
    }
    __syncthreads();                         // b2: transposes visible

    if (doA) STORE_OWN(hstA, hxE, gA, (aA & 1), aA + 1);
    if (doB) STORE_OWN(hstB, hxE, gB, (aB & 1), aB + 1);

    // poll-window: prefetch next x for both groups
    if (doA && t < 1023) {
      const float* xq = xbA + (size_t)(t + 1) * 128;
#pragma unroll
      for (int kt = 0; kt < 4; ++kt) {
        xaA[kt][0] = *(const float4*)(xq + kt * 32);
        xaA[kt][1] = *(const float4*)(xq + kt * 32 + 4);
      }
      xvA = true;
    } else xvA = false;
    if (doB && t < 1023) {
      const float* xq = xbB + (size_t)(t + 1) * 128;
#pragma unroll
      for (int kt = 0; kt < 4; ++kt) {
        xaB[kt][0] = *(const float4*)(xq + kt * 32);
        xaB[kt][1] = *(const float4*)(xq + kt * 32 + 4);
      }
      xvB = true;
    } else xvB = false;

    POLL2(hxE, doA, doB, (aA & 1), (aB & 1), aA + 1, aB + 1);
    __syncthreads();                         // b3: hstages populated

    if (doA) {
#pragma unroll
      for (int kt = 0; kt < 8; ++kt)
        hfA[kt] = *(const bf16x8*)&hstA[kt][lane][0];
      ++aA;
    }
    if (doB) {
#pragma unroll
      for (int kt = 0; kt < 8; ++kt)
        hfB[kt] = *(const bf16x8*)&hstB[kt][lane][0];
      ++aB;
    }
  }

  if (w < 2) {
    int kt = 2 * s + w;
    H8 h1; h1.v = hfA[kt];
    *(uint4v*)&hfin[((size_t)gA * 8 + kt) * 512 + lane * 8] = h1.q;
    H8 h2; h2.v = hfB[kt];
    *(uint4v*)&hfin[((size_t)gB * 8 + kt) * 512 + lane * 8] = h2.q;
  }
}

// =========================== decoder ======================================
__global__ __launch_bounds__(256) __attribute__((amdgpu_waves_per_eu(1, 1)))
void dec_rnn(const float* __restrict__ x,
             const ushort* __restrict__ Wd0f,
             const ushort* __restrict__ WdLf,
             const ushort* __restrict__ Udf,
             const float* __restrict__ bdec,
             const ushort* __restrict__ Wof,
             const float* __restrict__ bout,
             const ushort* __restrict__ hfin,
             ull* __restrict__ hxD,
             float* __restrict__ out) {
  __shared__ __align__(16) ushort hstA[8][64][8];
  __shared__ __align__(16) ushort hstB[8][64][8];

  const int tid = threadIdx.x;
  const int w = tid >> 6, lane = tid & 63;
  const int l15 = lane & 15, lkg = lane >> 4;
  const int bid = blockIdx.x;
  const int s = bid >> 3, p = bid & 7;
  const int gA = 2 * p, gB = 2 * p + 1;
  const int b0A = gA * 16, b0B = gB * 16;
  int ntf[4];
#pragma unroll
  for (int G = 0; G < 4; ++G) ntf[G] = G * 16 + s * 4 + w;

  const bf16x8* W0l = (const bf16x8*)Wd0f + lane;
  const bf16x8* WLl = (const bf16x8*)WdLf + lane;
  const bf16x8* Ul  = (const bf16x8*)Udf + lane;

  bf16x8 upin[8][4];                          // shared by A and B
#pragma unroll
  for (int kt = 0; kt < 8; ++kt)
#pragma unroll
    for (int G = 0; G < 4; ++G) upin[kt][G] = Ul[(kt * 64 + ntf[G]) * 64];

  bf16x8 w0pin[4][2];
#pragma unroll
  for (int G = 0; G < 4; ++G)
#pragma unroll
    for (int kt = 0; kt < 2; ++kt) w0pin[G][kt] = W0l[(kt * 64 + ntf[G]) * 64];

  f32x4 latA[4], latB[4];
  {
    bf16x8 ha[8], hb[8];
#pragma unroll
    for (int kt = 0; kt < 8; ++kt) {
      ha[kt] = *(const bf16x8*)&hfin[((size_t)gA * 8 + kt) * 512 + lane * 8];
      hb[kt] = *(const bf16x8*)&hfin[((size_t)gB * 8 + kt) * 512 + lane * 8];
    }
#pragma unroll
    for (int G = 0; G < 4; ++G) {
      float bd = bdec[ntf[G] * 16 + l15];
      latA[G] = (f32x4){bd, bd, bd, bd};
      latB[G] = (f32x4){bd, bd, bd, bd};
    }
#pragma unroll
    for (int kt = 0; kt < 8; ++kt)
#pragma unroll
      for (int G = 0; G < 4; ++G) {
        bf16x8 wl = WLl[(kt * 64 + ntf[G]) * 64];
        latA[G] = mfma16(ha[kt], wl, latA[G]);
        latB[G] = mfma16(hb[kt], wl, latB[G]);
      }
  }

  bf16x8 wofr[8];                             // W_out slice (wave 0), shared
  if (w == 0) {
#pragma unroll
    for (int kt = 0; kt < 8; ++kt)
      wofr[kt] = ((const bf16x8*)Wof)[(kt * 4 + s) * 64 + lane];
  }
  const float bo = bout[s * 16 + l15];

  float cA[4], cB[4];
  bf16x8 hfA[8], hfB[8];
#pragma unroll
  for (int q = 0; q < 4; ++q) { cA[q] = 0.f; cB[q] = 0.f; }
  H8 z_; z_.u[0] = 0; z_.u[1] = 0;
#pragma unroll
  for (int kt = 0; kt < 8; ++kt) { hfA[kt] = z_.v; hfB[kt] = z_.v; }

  const float* xbA = x + (size_t)(b0A + l15) * 1024 * 128 + lkg * 8;
  const float* xbB = x + (size_t)(b0B + l15) * 1024 * 128 + lkg * 8;
  const int kt_own = 2 * s + (w >> 1);
  const int lbase = (w & 1) * 32 + (l15 >> 3) * 16 + lkg * 4;
  const int jst = l15 & 7;

  float4 xaA[2][2], xaB[2][2];
  xaA[0][0] = *(const float4*)(xbA);      xaA[0][1] = *(const float4*)(xbA + 4);
  xaA[1][0] = *(const float4*)(xbA + 32); xaA[1][1] = *(const float4*)(xbA + 36);
  xaB[0][0] = *(const float4*)(xbB);      xaB[0][1] = *(const float4*)(xbB + 4);
  xaB[1][0] = *(const float4*)(xbB + 32); xaB[1][1] = *(const float4*)(xbB + 36);

  __syncthreads();

  for (int t = 0; t < 1024; ++t) {
    ushort hvA[4], hvB[4];

    {                                         // ---- A compute ----
      f32x4 acc[4];
#pragma unroll
      for (int G = 0; G < 4; ++G) acc[G] = latA[G];
      FragU xf[2];
#pragma unroll
      for (int kt = 0; kt < 2; ++kt) {
        xf[kt].us[0] = f2bf(xaA[kt][0].x); xf[kt].us[1] = f2bf(xaA[kt][0].y);
        xf[kt].us[2] = f2bf(xaA[kt][0].z); xf[kt].us[3] = f2bf(xaA[kt][0].w);
        xf[kt].us[4] = f2bf(xaA[kt][1].x); xf[kt].us[5] = f2bf(xaA[kt][1].y);
        xf[kt].us[6] = f2bf(xaA[kt][1].z); xf[kt].us[7] = f2bf(xaA[kt][1].w);
      }
#pragma unroll
      for (int kt = 0; kt < 2; ++kt)
#pragma unroll
        for (int G = 0; G < 4; ++G) acc[G] = mfma16(xf[kt].v, w0pin[G][kt], acc[G]);
#pragma unroll
      for (int kt = 0; kt < 8; ++kt)
#pragma unroll
        for (int G = 0; G < 4; ++G) acc[G] = mfma16(hfA[kt], upin[kt][G], acc[G]);
#pragma unroll
      for (int q = 0; q < 4; ++q) {
        float iv = sigf(acc[0][q]);
        float fv = sigf(acc[1][q]);
        float gv = fmaxf(acc[2][q], 0.f);
        float ov = sigf(acc[3][q]);
        float cn = fv * cA[q] + iv * gv;
        cA[q] = cn;
        hvA[q] = f2bf(ov * fmaxf(cn, 0.f));
      }
    }

    {                                         // ---- B compute ----
      f32x4 acc[4];
#pragma unroll
      for (int G = 0; G < 4; ++G) acc[G] = latB[G];
      FragU xf[2];
#pragma unroll
      for (int kt = 0; kt < 2; ++kt) {
        xf[kt].us[0] = f2bf(xaB[kt][0].x); xf[kt].us[1] = f2bf(xaB[kt][0].y);
        xf[kt].us[2] = f2bf(xaB[kt][0].z); xf[kt].us[3] = f2bf(xaB[kt][0].w);
        xf[kt].us[4] = f2bf(xaB[kt][1].x); xf[kt].us[5] = f2bf(xaB[kt][1].y);
        xf[kt].us[6] = f2bf(xaB[kt][1].z); xf[kt].us[7] = f2bf(xaB[kt][1].w);
      }
#pragma unroll
      for (int kt = 0; kt < 2; ++kt)
#pragma unroll
        for (int G = 0; G < 4; ++G) acc[G] = mfma16(xf[kt].v, w0pin[G][kt], acc[G]);
#pragma unroll
      for (int kt = 0; kt < 8; ++kt)
#pragma unroll
        for (int G = 0; G < 4; ++G) acc[G] = mfma16(hfB[kt], upin[kt][G], acc[G]);
#pragma unroll
      for (int q = 0; q < 4; ++q) {
        float iv = sigf(acc[0][q]);
        float fv = sigf(acc[1][q]);
        float gv = fmaxf(acc[2][q], 0.f);
        float ov = sigf(acc[3][q]);
        float cn = fv * cB[q] + iv * gv;
        cB[q] = cn;
        hvB[q] = f2bf(ov * fmaxf(cn, 0.f));
      }
    }

    __syncthreads();                          // b1
#pragma unroll
    for (int q = 0; q < 4; ++q) hstA[kt_own][lbase + q][jst] = hvA[q];
#pragma unroll
    for (int q = 0; q < 4; ++q) hstB[kt_own][lbase + q][jst] = hvB[q];
    __syncthreads();                          // b2

    STORE_OWN(hstA, hxD, gA, (t & 1), t + 1);
    STORE_OWN(hstB, hxD, gB, (t & 1), t + 1);

    // poll-window: out-proj(t-1) for BOTH groups on wave 0; x prefetch
    if (t > 0 && w == 0) {
      f32x4 oa = {bo, bo, bo, bo};
      f32x4 ob = {bo, bo, bo, bo};
#pragma unroll
      for (int kt = 0; kt < 8; ++kt) {
        oa = mfma16(hfA[kt], wofr[kt], oa);
        ob = mfma16(hfB[kt], wofr[kt], ob);
      }
#pragma unroll
      for (int q = 0; q < 4; ++q) {
        out[((size_t)(b0A + lkg * 4 + q) * 1024 + (t - 1)) * 64 + s * 16 + l15] = oa[q];
        out[((size_t)(b0B + lkg * 4 + q) * 1024 + (t - 1)) * 64 + s * 16 + l15] = ob[q];
      }
    }
    if (t < 1023) {
      const float* xqA = xbA + (size_t)(t + 1) * 128;
      const float* xqB = xbB + (size_t)(t + 1) * 128;
      xaA[0][0] = *(const float4*)(xqA);      xaA[0][1] = *(const float4*)(xqA + 4);
      xaA[1][0] = *(const float4*)(xqA + 32); xaA[1][1] = *(const float4*)(xqA + 36);
      xaB[0][0] = *(const float4*)(xqB);      xaB[0][1] = *(const float4*)(xqB + 4);
      xaB[1][0] = *(const float4*)(xqB + 32); xaB[1][1] = *(const float4*)(xqB + 36);
    }

    POLL2(hxD, true, true, (t & 1), (t & 1), t + 1, t + 1);
    __syncthreads();                          // b3

#pragma unroll
    for (int kt = 0; kt < 8; ++kt) {
      hfA[kt] = *(const bf16x8*)&hstA[kt][lane][0];
      hfB[kt] = *(const bf16x8*)&hstB[kt][lane][0];
    }
  }

  if (w == 0) {                               // final out-proj (t=1023)
    f32x4 oa = {bo, bo, bo, bo};
    f32x4 ob = {bo, bo, bo, bo};
#pragma unroll
    for (int kt = 0; kt < 8; ++kt) {
      oa = mfma16(hfA[kt], wofr[kt], oa);
      ob = mfma16(hfB[kt], wofr[kt], ob);
    }
#pragma unroll
    for (int q = 0; q < 4; ++q) {
      out[((size_t)(b0A + lkg * 4 + q) * 1024 + 1023) * 64 + s * 16 + l15] = oa[q];
      out[((size_t)(b0B + lkg * 4 + q) * 1024 + 1023) * 64 + s * 16 + l15] = ob[q];
    }
  }
}

extern "C" void kernel_launch(void* const* d_in, const int* in_sizes, int n_in,
                              void* d_out, int out_size, void* d_ws, size_t ws_size,
                              hipStream_t stream) {
  const float* inputs = (const float*)d_in[0];
  const float* W_enc  = (const float*)d_in[1];
  const float* U_enc  = (const float*)d_in[2];
  const float* b_enc  = (const float*)d_in[3];
  const float* W_dec  = (const float*)d_in[4];
  const float* U_dec  = (const float*)d_in[5];
  const float* b_dec  = (const float*)d_in[6];
  const float* W_out  = (const float*)d_in[7];
  const float* b_out  = (const float*)d_in[8];

  char* ws = (char*)d_ws;
  ushort* Uef   = (ushort*)(ws + 0);        // 512K
  ushort* Udf   = (ushort*)(ws + 524288);   // 512K
  ushort* Wef   = (ushort*)(ws + 1048576);  // 256K
  ushort* Wd0f  = (ushort*)(ws + 1310720);  // 128K
  ushort* WdLf  = (ushort*)(ws + 1441792);  // 512K
  ushort* Wof   = (ushort*)(ws + 1966080);  // 32K
  ushort* hfin  = (ushort*)(ws + 1998848);  // 128K
  unsigned int* fmask = (unsigned int*)(ws + 2129920);  // 64K
  ull*    hxE   = (ull*)(ws + 2195456);     // 384K tagged
  ull*    hxD   = (ull*)(ws + 2588672);     // 384K tagged

  mask_flags<<<1024, 256, 0, stream>>>(inputs, fmask);
  pack_frags<<<128, 256, 0, stream>>>(U_enc, Uef, 256, 1024);
  pack_frags<<<128, 256, 0, stream>>>(U_dec, Udf, 256, 1024);
  pack_frags<<<128, 256, 0, stream>>>(W_enc, Wef, 128, 1024);
  pack_frags<<<128, 256, 0, stream>>>(W_dec, Wd0f, 64, 1024);
  pack_frags<<<128, 256, 0, stream>>>(W_dec + 64 * 1024, WdLf, 256, 1024);
  pack_frags<<<32, 256, 0, stream>>>(W_out, Wof, 256, 64);

  enc_rnn<<<32, 256, 0, stream>>>(inputs, Wef, Uef, b_enc, fmask, hxE, hfin);
  dec_rnn<<<32, 256, 0, stream>>>(inputs, Wd0f, WdLf, Udf, b_dec, Wof, b_out,
                                  hfin, hxD, (float*)d_out);
}